// Round 5
// baseline (101.751 us; speedup 1.0000x reference)
//
#include <hip/hip_runtime.h>

// VQC 12-qubit statevector, batch=1024. One block = 256 thr = 4 waves = ONE
// batch element; each wave holds 16 float2 amps (quarter state). 4 blocks/CU
// -> 16 waves/CU = 4 waves/SIMD (the R2/R3/R4 scaling law: time ~ 1/(waves/SIMD)).
// Flat index i (12 bits), qubit q <-> bit (11-q).
// Layout A: b11b10 = w (q0,q1); b9..b6 = reg (q2..q5); b5..b0 = lane (q6..q11)
// Layout B: b11b10 = w (q0,q1); b9..b4 = lane (q2..q7); b3..b0 = reg (q8..q11)
// Layer 0 (all single-qubit gates) folds into the closed-form product-state
// init (state is a product state until the first CNOT). Per remaining layer:
// BA exchange fuses the CNOT-chain Gray permutation x=y^(y>>1) AND that
// layer's Y_q0,Y_q1 (4-point read, Y0xY1 coeffs); Y q2..q5 in-reg [A];
// AB exchange fuses Y_q6,Y_q7 (contiguous 4-point read, wave-local, no
// internal barrier); Y q8..q11 in-reg [B]; fused Z (all 12, one complex
// factor per amp). Last layer's Zs are no-ops for the |amp|^2 readout.

#define PI_F 3.14159265358979323846f
#define NR 16
#define ROWP_BA 129   // odd stride -> BA write banks spread
#define ROWP_AB 66    // even -> AB 4-point reads stay 16B aligned (b128)

__device__ __forceinline__ float2 cmul(float2 a, float2 b) {
    return make_float2(a.x*b.x - a.y*b.y, a.x*b.y + a.y*b.x);
}

template<int RB>
__device__ __forceinline__ void ypow_reg(float2 (&a)[NR], float c, float s) {
    #pragma unroll
    for (int r0 = 0; r0 < NR; ++r0) {
        if ((r0 >> RB) & 1) continue;
        const int r1 = r0 | (1 << RB);
        float2 a0 = a[r0], a1 = a[r1];
        a[r0] = make_float2(c*a0.x - s*a1.x, c*a0.y - s*a1.y);
        a[r1] = make_float2(s*a0.x + c*a1.x, s*a0.y + c*a1.y);
    }
}

// Layout B -> A. Fuses CNOT chain (new[y] = old[y ^ (y>>1)], 12-bit) and the
// NEXT-applied Y_q0, Y_q1 (act on bits 11,10 after the permutation).
// Staging slot, addressed by the INPUT's own bits:
//   slot = (x8..x4)*ROWP_BA + (x3..x0)*8 + x9*4 + ((x11<<1)|x10)
__device__ __forceinline__ void exchange_BA(float2 (&a)[NR], float2* buf,
                                            int w, int lane,
                                            float c0, float s0, float c1, float s1,
                                            bool first) {
    if (!first) __syncthreads();           // prior block-wide reads done
    const int wbase = (lane & 31) * ROWP_BA + (lane >> 5) * 4 + w;
    #pragma unroll
    for (int r = 0; r < NR; ++r)
        buf[wbase + r * 8] = a[r];
    __syncthreads();
    // K[(y11,y10)][(v0,v1)] = Y0[y11,v0] * Y1[y10,v1], Y = [[c,-s],[s,c]]
    const float y0a = (w & 2) ? s0 : c0;   // v0=0
    const float y0b = (w & 2) ? c0 : -s0;  // v0=1
    const float y1a = (w & 1) ? s1 : c1;   // v1=0
    const float y1b = (w & 1) ? c1 : -s1;  // v1=1
    const float K00 = y0a*y1a, K01 = y0a*y1b, K10 = y0b*y1a, K11 = y0b*y1b;
    #pragma unroll
    for (int rp = 0; rp < NR; ++rp) {
        const int ylow = (rp << 6) | lane;       // y bits 9..0 (w'-independent)
        const int t = ylow ^ (ylow >> 1);        // x bits 8..0 (t&511); t9 unused
        const int base = ((t >> 4) & 31) * ROWP_BA + (t & 15) * 8;
        const int x9 = (rp >> 3) & 1;            // y9 ^ v1 with v1=0
        // (v0,v1) -> w_in=(v0, v0^v1): (0,0)->0, (0,1)->1, (1,0)->3, (1,1)->2
        float2 i00 = buf[base + x9 * 4 + 0];
        float2 i01 = buf[base + (x9 ^ 1) * 4 + 1];
        float2 i10 = buf[base + x9 * 4 + 3];
        float2 i11 = buf[base + (x9 ^ 1) * 4 + 2];
        a[rp] = make_float2(K00*i00.x + K01*i01.x + K10*i10.x + K11*i11.x,
                            K00*i00.y + K01*i01.y + K10*i10.y + K11*i11.y);
    }
}

// Layout A -> B, fusing Y_q6, Y_q7. Wave-local (own region), write->read
// in-order within the wave => no internal barrier (validated pattern, R4).
__device__ __forceinline__ void exchange_AB(float2 (&a)[NR], float2* wbuf,
                                            int lane,
                                            float c6, float s6, float c7, float s7) {
    __syncthreads();                        // prior block-wide BA reads done
    const int wslot = (lane & 15) * 4 + (lane >> 4);
    #pragma unroll
    for (int r = 0; r < NR; ++r)
        wbuf[r * ROWP_AB + wslot] = a[r];
    const int j = lane & 3;                 // new (q6,q7) values
    const float e0 = (j & 2) ? s6 : c6;     // old q6 = 0
    const float e1 = (j & 2) ? c6 : -s6;    // old q6 = 1
    const float f0 = (j & 1) ? s7 : c7;
    const float f1 = (j & 1) ? c7 : -s7;
    const float C0 = e0*f0, C1 = e0*f1, C2 = e1*f0, C3 = e1*f1;
    const int rbase = (lane >> 2) * ROWP_AB;
    #pragma unroll
    for (int rp = 0; rp < NR; ++rp) {
        float2 p0 = wbuf[rbase + rp * 4 + 0];   // contiguous: 2x ds_read_b128
        float2 p1 = wbuf[rbase + rp * 4 + 1];
        float2 p2 = wbuf[rbase + rp * 4 + 2];
        float2 p3 = wbuf[rbase + rp * 4 + 3];
        a[rp] = make_float2(C0*p0.x + C1*p1.x + C2*p2.x + C3*p3.x,
                            C0*p0.y + C1*p1.y + C2*p2.y + C3*p3.y);
    }
}

// Fused Z, all 12 qubits, layout B.
__device__ __forceinline__ void fused_z_B(float2 (&a)[NR], int w, int lane,
                                          const float* __restrict__ th) {
    float alpha = 0.0f;
    if (w & 2) alpha += th[1];                  // q0
    if (w & 1) alpha += th[3];                  // q1
    #pragma unroll
    for (int k = 0; k < 6; ++k)                 // lane bit k <-> q(7-k)
        alpha += ((lane >> k) & 1) ? th[2*(7-k)+1] : 0.0f;
    float2 cA; __sincosf(PI_F * alpha, &cA.y, &cA.x);
    float2 z8, z9, z10, z11;
    __sincosf(PI_F * th[17], &z8.y,  &z8.x);
    __sincosf(PI_F * th[19], &z9.y,  &z9.x);
    __sincosf(PI_F * th[21], &z10.y, &z10.x);
    __sincosf(PI_F * th[23], &z11.y, &z11.x);
    float2 hi[4], lo[4];
    hi[0] = cA;                    hi[1] = cmul(cA, z9);
    hi[2] = cmul(cA, z8);          hi[3] = cmul(hi[2], z9);
    lo[0] = make_float2(1.f, 0.f); lo[1] = z11;
    lo[2] = z10;                   lo[3] = cmul(z10, z11);
    #pragma unroll
    for (int r = 0; r < NR; ++r)
        a[r] = cmul(cmul(a[r], hi[r >> 2]), lo[r & 3]);
}

// Product-state init in layout B: per qubit u_q = Z^z0q . Y^y0q . (1, e^{i pi x_q}),
// norm 2^-6 folded in. The whole of layer 0's single-qubit gates live here.
__device__ __forceinline__ void encode_init(float2 (&a)[NR], int w, int lane,
                                            const float* __restrict__ x,
                                            const float* __restrict__ th0) {
    float2 F = make_float2(0.015625f, 0.0f);
    #pragma unroll
    for (int q = 0; q < 8; ++q) {
        float2 ex; __sincosf(PI_F * x[q], &ex.y, &ex.x);
        float sy, cy; __sincosf(0.5f * PI_F * th0[2*q], &sy, &cy);
        float2 cz; __sincosf(PI_F * th0[2*q+1], &cz.y, &cz.x);
        float2 u0 = make_float2(cy - sy*ex.x, -sy*ex.y);
        float2 u1 = cmul(cz, make_float2(sy + cy*ex.x, cy*ex.y));
        int bit;
        if (q == 0)      bit = (w >> 1) & 1;
        else if (q == 1) bit = w & 1;
        else             bit = (lane >> (7 - q)) & 1;
        F = cmul(F, bit ? u1 : u0);
    }
    float2 v0[4], v1[4];                        // q8..q11
    #pragma unroll
    for (int q = 8; q < 12; ++q) {
        float2 ex; __sincosf(PI_F * x[q], &ex.y, &ex.x);
        float sy, cy; __sincosf(0.5f * PI_F * th0[2*q], &sy, &cy);
        float2 cz; __sincosf(PI_F * th0[2*q+1], &cz.y, &cz.x);
        v0[q-8] = make_float2(cy - sy*ex.x, -sy*ex.y);
        v1[q-8] = cmul(cz, make_float2(sy + cy*ex.x, cy*ex.y));
    }
    float2 hi[4], lo[4];
    hi[0] = cmul(v0[0], v0[1]); hi[1] = cmul(v0[0], v1[1]);
    hi[2] = cmul(v1[0], v0[1]); hi[3] = cmul(v1[0], v1[1]);
    lo[0] = cmul(v0[2], v0[3]); lo[1] = cmul(v0[2], v1[3]);
    lo[2] = cmul(v1[2], v0[3]); lo[3] = cmul(v1[2], v1[3]);
    #pragma unroll
    for (int t = 0; t < 4; ++t) hi[t] = cmul(F, hi[t]);
    #pragma unroll
    for (int r = 0; r < NR; ++r)
        a[r] = cmul(hi[r >> 2], lo[r & 3]);
}

__global__ __launch_bounds__(256, 4) void vqc_kernel(
    const float* __restrict__ inputs,   // [1024,12]
    const float* __restrict__ thetas,   // [72] = [3][12][2]
    float* __restrict__ out)            // [1024,12]
{
    __shared__ __align__(16) float2 buf[4 * NR * ROWP_AB];  // 4224 f2 = 33,792 B (BA needs 4127)
    __shared__ float redBuf[4][12];

    const int b = blockIdx.x;
    const int tid = threadIdx.x;
    const int w = tid >> 6;
    const int lane = tid & 63;
    const float* x = inputs + b * 12;
    const float* th1 = thetas + 24;
    const float* th2 = thetas + 48;

    float2 a[NR];
    encode_init(a, w, lane, x, thetas);     // all of layer 0's 1q gates

    // Layer-0 CNOT chain, fused with layer-1 Y_q0, Y_q1
    { float s0,c0,s1,c1;
      __sincosf(0.5f*PI_F*th1[0], &s0, &c0);
      __sincosf(0.5f*PI_F*th1[2], &s1, &c1);
      exchange_BA(a, buf, w, lane, c0, s0, c1, s1, true); }

    // ---- Layer 1 ----
    { float s,c; __sincosf(0.5f*PI_F*th1[4],  &s,&c); ypow_reg<3>(a,c,s); }  // q2
    { float s,c; __sincosf(0.5f*PI_F*th1[6],  &s,&c); ypow_reg<2>(a,c,s); }  // q3
    { float s,c; __sincosf(0.5f*PI_F*th1[8],  &s,&c); ypow_reg<1>(a,c,s); }  // q4
    { float s,c; __sincosf(0.5f*PI_F*th1[10], &s,&c); ypow_reg<0>(a,c,s); }  // q5
    { float s6,c6,s7,c7;
      __sincosf(0.5f*PI_F*th1[12], &s6,&c6);
      __sincosf(0.5f*PI_F*th1[14], &s7,&c7);
      exchange_AB(a, buf + w * (NR * ROWP_AB), lane, c6, s6, c7, s7); }
    { float s,c; __sincosf(0.5f*PI_F*th1[16], &s,&c); ypow_reg<3>(a,c,s); }  // q8
    { float s,c; __sincosf(0.5f*PI_F*th1[18], &s,&c); ypow_reg<2>(a,c,s); }  // q9
    { float s,c; __sincosf(0.5f*PI_F*th1[20], &s,&c); ypow_reg<1>(a,c,s); }  // q10
    { float s,c; __sincosf(0.5f*PI_F*th1[22], &s,&c); ypow_reg<0>(a,c,s); }  // q11
    fused_z_B(a, w, lane, th1);

    // Layer-1 CNOT chain, fused with layer-2 Y_q0, Y_q1
    { float s0,c0,s1,c1;
      __sincosf(0.5f*PI_F*th2[0], &s0, &c0);
      __sincosf(0.5f*PI_F*th2[2], &s1, &c1);
      exchange_BA(a, buf, w, lane, c0, s0, c1, s1, false); }

    // ---- Layer 2 (no CNOT; Zs dropped — diagonal before |amp|^2) ----
    { float s,c; __sincosf(0.5f*PI_F*th2[4],  &s,&c); ypow_reg<3>(a,c,s); }
    { float s,c; __sincosf(0.5f*PI_F*th2[6],  &s,&c); ypow_reg<2>(a,c,s); }
    { float s,c; __sincosf(0.5f*PI_F*th2[8],  &s,&c); ypow_reg<1>(a,c,s); }
    { float s,c; __sincosf(0.5f*PI_F*th2[10], &s,&c); ypow_reg<0>(a,c,s); }
    { float s6,c6,s7,c7;
      __sincosf(0.5f*PI_F*th2[12], &s6,&c6);
      __sincosf(0.5f*PI_F*th2[14], &s7,&c7);
      exchange_AB(a, buf + w * (NR * ROWP_AB), lane, c6, s6, c7, s7); }
    { float s,c; __sincosf(0.5f*PI_F*th2[16], &s,&c); ypow_reg<3>(a,c,s); }
    { float s,c; __sincosf(0.5f*PI_F*th2[18], &s,&c); ypow_reg<2>(a,c,s); }
    { float s,c; __sincosf(0.5f*PI_F*th2[20], &s,&c); ypow_reg<1>(a,c,s); }
    { float s,c; __sincosf(0.5f*PI_F*th2[22], &s,&c); ypow_reg<0>(a,c,s); }

    // ---- Readout (layout B): q0=w>>1, q1=w&1, q2..q7=lane bits 5..0, q8..11=reg bits 3..0
    float totalP = 0.0f;
    float D[4] = {0, 0, 0, 0};
    #pragma unroll
    for (int r = 0; r < NR; ++r) {
        const float p = a[r].x * a[r].x + a[r].y * a[r].y;
        totalP += p;
        #pragma unroll
        for (int j = 0; j < 4; ++j)
            D[j] += ((r >> j) & 1) ? -p : p;
    }
    #pragma unroll
    for (int q = 0; q < 12; ++q) {
        float v;
        if (q == 0)      v = (w & 2) ? -totalP : totalP;
        else if (q == 1) v = (w & 1) ? -totalP : totalP;
        else if (q <= 7) v = ((lane >> (7 - q)) & 1) ? -totalP : totalP;
        else             v = D[11 - q];
        #pragma unroll
        for (int off = 32; off >= 1; off >>= 1)
            v += __shfl_xor(v, off, 64);
        if (lane == 0) redBuf[w][q] = v;
    }
    __syncthreads();
    if (tid < 12)
        out[b * 12 + tid] = redBuf[0][tid] + redBuf[1][tid]
                          + redBuf[2][tid] + redBuf[3][tid];
}

extern "C" void kernel_launch(void* const* d_in, const int* in_sizes, int n_in,
                              void* d_out, int out_size, void* d_ws, size_t ws_size,
                              hipStream_t stream) {
    const float* inputs = (const float*)d_in[0];   // [1024,12] f32
    const float* thetas = (const float*)d_in[1];   // [72] f32
    float* out = (float*)d_out;                    // [1024,12] f32
    vqc_kernel<<<dim3(1024), dim3(256), 0, stream>>>(inputs, thetas, out);
}

// Round 6
// 78.386 us; speedup vs baseline: 1.2981x; 1.2981x over previous
//
#include <hip/hip_runtime.h>

// VQC 12-qubit statevector, batch=1024. One block = 256 thr = 4 waves = ONE
// batch element; each wave holds 16 float2 amps. Grid 1024 = 4 blocks/CU ->
// 16 waves/CU = 4 waves/SIMD (R2-R5 scaling law: time ~ 1/(waves/SIMD)).
// Flat index i (12 bits), qubit q <-> bit (11-q).
// Layout A: b11b10 = w (q0,q1); b9..b6 = reg (q2..q5); b5..b0 = lane (q6..q11)
// Layout B: b11b10 = w (q0,q1); b9..b4 = lane (q2..q7); b3..b0 = reg (q8..q11)
// Layer 0 folds into the closed-form product-state init. Per remaining layer:
// BA exchange fuses CNOT Gray perm (new[y]=old[y^(y>>1)]) + that layer's
// Y_q0,Y_q1; Y q2..q5 in-reg [A]; AB exchange fuses Y_q6,Y_q7 (wave-local);
// Y q8..q11 in-reg [B]; fused Z. Last layer's Zs dropped (|amp|^2 readout).
// R6 vs R5: (1) plain __launch_bounds__(256) - the (256,4) min-waves arg
// clamped VGPR to 64 and spilled 51 MB to scratch; (2) BA slotting redone in
// R3's proven zero-conflict style: fine bits at stride-1 f2, groups at odd
// stride 17 -> bank = 2*((g + r) mod 16), <=2-way (R5's was ~16-way, 1.6e7).

#define PI_F 3.14159265358979323846f
#define NR 16
#define ROWP_AB 66

__device__ __forceinline__ float2 cmul(float2 a, float2 b) {
    return make_float2(a.x*b.x - a.y*b.y, a.x*b.y + a.y*b.x);
}

template<int RB>
__device__ __forceinline__ void ypow_reg(float2 (&a)[NR], float c, float s) {
    #pragma unroll
    for (int r0 = 0; r0 < NR; ++r0) {
        if ((r0 >> RB) & 1) continue;
        const int r1 = r0 | (1 << RB);
        float2 a0 = a[r0], a1 = a[r1];
        a[r0] = make_float2(c*a0.x - s*a1.x, c*a0.y - s*a1.y);
        a[r1] = make_float2(s*a0.x + c*a1.x, s*a0.y + c*a1.y);
    }
}

// Layout B -> A. Fuses CNOT chain (new[y] = old[y ^ (y>>1)], 12-bit) and the
// next-applied Y_q0, Y_q1. Slot keyed by the input's own bits:
//   slot = x9*2176 + v1*1088 + v0*544 + (x8..x4)*17 + (x3..x0)
// where v0 = x11 (= y11), v1 = x10^x11 (= y10). Reader output (w',rp,lane):
// tap (v0,v1) lives in region x9 = y9^v1, subregion v1, subslot v0.
__device__ __forceinline__ void exchange_BA(float2 (&a)[NR], float2* buf,
                                            int w, int lane,
                                            float c0, float s0, float c1, float s1,
                                            bool first) {
    if (!first) __syncthreads();           // prior block-wide reads done
    {
        const int x9 = lane >> 5;
        const int v0 = (w >> 1) & 1;
        const int v1 = v0 ^ (w & 1);
        const int wbase = x9 * 2176 + v1 * 1088 + v0 * 544 + (lane & 31) * 17;
        #pragma unroll
        for (int r = 0; r < NR; ++r)
            buf[wbase + r] = a[r];
    }
    __syncthreads();
    // K[(y11,y10)][(v0,v1)] = Y0[y11,v0] * Y1[y10,v1], Y = [[c,-s],[s,c]]
    const float y0a = (w & 2) ? s0 : c0;   // v0=0
    const float y0b = (w & 2) ? c0 : -s0;  // v0=1
    const float y1a = (w & 1) ? s1 : c1;   // v1=0
    const float y1b = (w & 1) ? c1 : -s1;  // v1=1
    const float K00 = y0a*y1a, K01 = y0a*y1b, K10 = y0b*y1a, K11 = y0b*y1b;
    #pragma unroll
    for (int rp = 0; rp < NR; ++rp) {
        const int ylow = (rp << 6) | lane;        // y bits 9..0
        const int t = (ylow ^ (ylow >> 1)) & 511; // x bits 8..0
        const int y9 = (rp >> 3) & 1;
        const int gbase = ((t >> 4) & 31) * 17 + (t & 15);
        float2 i00 = buf[ y9      * 2176           + gbase];  // v0=0,v1=0
        float2 i10 = buf[ y9      * 2176 +     544 + gbase];  // v0=1,v1=0
        float2 i01 = buf[(y9 ^ 1) * 2176 + 1088    + gbase];  // v0=0,v1=1
        float2 i11 = buf[(y9 ^ 1) * 2176 + 1632    + gbase];  // v0=1,v1=1
        a[rp] = make_float2(K00*i00.x + K01*i01.x + K10*i10.x + K11*i11.x,
                            K00*i00.y + K01*i01.y + K10*i10.y + K11*i11.y);
    }
}

// Layout A -> B, fusing Y_q6, Y_q7. Wave-local (own region), write->read
// in-order within the wave => no internal barrier.
__device__ __forceinline__ void exchange_AB(float2 (&a)[NR], float2* wbuf,
                                            int lane,
                                            float c6, float s6, float c7, float s7) {
    __syncthreads();                        // prior block-wide BA reads done
    const int wslot = (lane & 15) * 4 + (lane >> 4);
    #pragma unroll
    for (int r = 0; r < NR; ++r)
        wbuf[r * ROWP_AB + wslot] = a[r];
    const int j = lane & 3;                 // new (q6,q7) values
    const float e0 = (j & 2) ? s6 : c6;     // old q6 = 0
    const float e1 = (j & 2) ? c6 : -s6;    // old q6 = 1
    const float f0 = (j & 1) ? s7 : c7;
    const float f1 = (j & 1) ? c7 : -s7;
    const float C0 = e0*f0, C1 = e0*f1, C2 = e1*f0, C3 = e1*f1;
    const int rbase = (lane >> 2) * ROWP_AB;
    #pragma unroll
    for (int rp = 0; rp < NR; ++rp) {
        float2 p0 = wbuf[rbase + rp * 4 + 0];   // 2x ds_read_b128, 4-lane bcast
        float2 p1 = wbuf[rbase + rp * 4 + 1];
        float2 p2 = wbuf[rbase + rp * 4 + 2];
        float2 p3 = wbuf[rbase + rp * 4 + 3];
        a[rp] = make_float2(C0*p0.x + C1*p1.x + C2*p2.x + C3*p3.x,
                            C0*p0.y + C1*p1.y + C2*p2.y + C3*p3.y);
    }
}

// Fused Z, all 12 qubits, layout B.
__device__ __forceinline__ void fused_z_B(float2 (&a)[NR], int w, int lane,
                                          const float* __restrict__ th) {
    float alpha = 0.0f;
    if (w & 2) alpha += th[1];                  // q0
    if (w & 1) alpha += th[3];                  // q1
    #pragma unroll
    for (int k = 0; k < 6; ++k)                 // lane bit k <-> q(7-k)
        alpha += ((lane >> k) & 1) ? th[2*(7-k)+1] : 0.0f;
    float2 cA; __sincosf(PI_F * alpha, &cA.y, &cA.x);
    float2 z8, z9, z10, z11;
    __sincosf(PI_F * th[17], &z8.y,  &z8.x);
    __sincosf(PI_F * th[19], &z9.y,  &z9.x);
    __sincosf(PI_F * th[21], &z10.y, &z10.x);
    __sincosf(PI_F * th[23], &z11.y, &z11.x);
    float2 hi[4], lo[4];
    hi[0] = cA;                    hi[1] = cmul(cA, z9);
    hi[2] = cmul(cA, z8);          hi[3] = cmul(hi[2], z9);
    lo[0] = make_float2(1.f, 0.f); lo[1] = z11;
    lo[2] = z10;                   lo[3] = cmul(z10, z11);
    #pragma unroll
    for (int r = 0; r < NR; ++r)
        a[r] = cmul(cmul(a[r], hi[r >> 2]), lo[r & 3]);
}

// Product-state init in layout B: per qubit u_q = Z^z0q . Y^y0q . (1, e^{i pi x_q}),
// norm 2^-6 folded in. All of layer 0's single-qubit gates live here.
__device__ __forceinline__ void encode_init(float2 (&a)[NR], int w, int lane,
                                            const float* __restrict__ x,
                                            const float* __restrict__ th0) {
    float2 F = make_float2(0.015625f, 0.0f);
    #pragma unroll
    for (int q = 0; q < 8; ++q) {
        float2 ex; __sincosf(PI_F * x[q], &ex.y, &ex.x);
        float sy, cy; __sincosf(0.5f * PI_F * th0[2*q], &sy, &cy);
        float2 cz; __sincosf(PI_F * th0[2*q+1], &cz.y, &cz.x);
        float2 u0 = make_float2(cy - sy*ex.x, -sy*ex.y);
        float2 u1 = cmul(cz, make_float2(sy + cy*ex.x, cy*ex.y));
        int bit;
        if (q == 0)      bit = (w >> 1) & 1;
        else if (q == 1) bit = w & 1;
        else             bit = (lane >> (7 - q)) & 1;
        F = cmul(F, bit ? u1 : u0);
    }
    float2 v0[4], v1[4];                        // q8..q11
    #pragma unroll
    for (int q = 8; q < 12; ++q) {
        float2 ex; __sincosf(PI_F * x[q], &ex.y, &ex.x);
        float sy, cy; __sincosf(0.5f * PI_F * th0[2*q], &sy, &cy);
        float2 cz; __sincosf(PI_F * th0[2*q+1], &cz.y, &cz.x);
        v0[q-8] = make_float2(cy - sy*ex.x, -sy*ex.y);
        v1[q-8] = cmul(cz, make_float2(sy + cy*ex.x, cy*ex.y));
    }
    float2 hi[4], lo[4];
    hi[0] = cmul(v0[0], v0[1]); hi[1] = cmul(v0[0], v1[1]);
    hi[2] = cmul(v1[0], v0[1]); hi[3] = cmul(v1[0], v1[1]);
    lo[0] = cmul(v0[2], v0[3]); lo[1] = cmul(v0[2], v1[3]);
    lo[2] = cmul(v1[2], v0[3]); lo[3] = cmul(v1[2], v1[3]);
    #pragma unroll
    for (int t = 0; t < 4; ++t) hi[t] = cmul(F, hi[t]);
    #pragma unroll
    for (int r = 0; r < NR; ++r)
        a[r] = cmul(hi[r >> 2], lo[r & 3]);
}

__global__ __launch_bounds__(256) void vqc_kernel(
    const float* __restrict__ inputs,   // [1024,12]
    const float* __restrict__ thetas,   // [72] = [3][12][2]
    float* __restrict__ out)            // [1024,12]
{
    __shared__ __align__(16) float2 buf[4352];   // BA needs 4352 f2; AB needs 4224
    __shared__ float redBuf[4][12];

    const int b = blockIdx.x;
    const int tid = threadIdx.x;
    const int w = tid >> 6;
    const int lane = tid & 63;
    const float* x = inputs + b * 12;
    const float* th1 = thetas + 24;
    const float* th2 = thetas + 48;

    float2 a[NR];
    encode_init(a, w, lane, x, thetas);     // all of layer 0's 1q gates

    // Layer-0 CNOT chain, fused with layer-1 Y_q0, Y_q1
    { float s0,c0,s1,c1;
      __sincosf(0.5f*PI_F*th1[0], &s0, &c0);
      __sincosf(0.5f*PI_F*th1[2], &s1, &c1);
      exchange_BA(a, buf, w, lane, c0, s0, c1, s1, true); }

    // ---- Layer 1 ----
    { float s,c; __sincosf(0.5f*PI_F*th1[4],  &s,&c); ypow_reg<3>(a,c,s); }  // q2
    { float s,c; __sincosf(0.5f*PI_F*th1[6],  &s,&c); ypow_reg<2>(a,c,s); }  // q3
    { float s,c; __sincosf(0.5f*PI_F*th1[8],  &s,&c); ypow_reg<1>(a,c,s); }  // q4
    { float s,c; __sincosf(0.5f*PI_F*th1[10], &s,&c); ypow_reg<0>(a,c,s); }  // q5
    { float s6,c6,s7,c7;
      __sincosf(0.5f*PI_F*th1[12], &s6,&c6);
      __sincosf(0.5f*PI_F*th1[14], &s7,&c7);
      exchange_AB(a, buf + w * (NR * ROWP_AB), lane, c6, s6, c7, s7); }
    { float s,c; __sincosf(0.5f*PI_F*th1[16], &s,&c); ypow_reg<3>(a,c,s); }  // q8
    { float s,c; __sincosf(0.5f*PI_F*th1[18], &s,&c); ypow_reg<2>(a,c,s); }  // q9
    { float s,c; __sincosf(0.5f*PI_F*th1[20], &s,&c); ypow_reg<1>(a,c,s); }  // q10
    { float s,c; __sincosf(0.5f*PI_F*th1[22], &s,&c); ypow_reg<0>(a,c,s); }  // q11
    fused_z_B(a, w, lane, th1);

    // Layer-1 CNOT chain, fused with layer-2 Y_q0, Y_q1
    { float s0,c0,s1,c1;
      __sincosf(0.5f*PI_F*th2[0], &s0, &c0);
      __sincosf(0.5f*PI_F*th2[2], &s1, &c1);
      exchange_BA(a, buf, w, lane, c0, s0, c1, s1, false); }

    // ---- Layer 2 (no CNOT; Zs dropped — diagonal before |amp|^2) ----
    { float s,c; __sincosf(0.5f*PI_F*th2[4],  &s,&c); ypow_reg<3>(a,c,s); }
    { float s,c; __sincosf(0.5f*PI_F*th2[6],  &s,&c); ypow_reg<2>(a,c,s); }
    { float s,c; __sincosf(0.5f*PI_F*th2[8],  &s,&c); ypow_reg<1>(a,c,s); }
    { float s,c; __sincosf(0.5f*PI_F*th2[10], &s,&c); ypow_reg<0>(a,c,s); }
    { float s6,c6,s7,c7;
      __sincosf(0.5f*PI_F*th2[12], &s6,&c6);
      __sincosf(0.5f*PI_F*th2[14], &s7,&c7);
      exchange_AB(a, buf + w * (NR * ROWP_AB), lane, c6, s6, c7, s7); }
    { float s,c; __sincosf(0.5f*PI_F*th2[16], &s,&c); ypow_reg<3>(a,c,s); }
    { float s,c; __sincosf(0.5f*PI_F*th2[18], &s,&c); ypow_reg<2>(a,c,s); }
    { float s,c; __sincosf(0.5f*PI_F*th2[20], &s,&c); ypow_reg<1>(a,c,s); }
    { float s,c; __sincosf(0.5f*PI_F*th2[22], &s,&c); ypow_reg<0>(a,c,s); }

    // ---- Readout (layout B): q0=w>>1, q1=w&1, q2..q7=lane bits 5..0, q8..11=reg bits 3..0
    float totalP = 0.0f;
    float D[4] = {0, 0, 0, 0};
    #pragma unroll
    for (int r = 0; r < NR; ++r) {
        const float p = a[r].x * a[r].x + a[r].y * a[r].y;
        totalP += p;
        #pragma unroll
        for (int j = 0; j < 4; ++j)
            D[j] += ((r >> j) & 1) ? -p : p;
    }
    #pragma unroll
    for (int q = 0; q < 12; ++q) {
        float v;
        if (q == 0)      v = (w & 2) ? -totalP : totalP;
        else if (q == 1) v = (w & 1) ? -totalP : totalP;
        else if (q <= 7) v = ((lane >> (7 - q)) & 1) ? -totalP : totalP;
        else             v = D[11 - q];
        #pragma unroll
        for (int off = 32; off >= 1; off >>= 1)
            v += __shfl_xor(v, off, 64);
        if (lane == 0) redBuf[w][q] = v;
    }
    __syncthreads();
    if (tid < 12)
        out[b * 12 + tid] = redBuf[0][tid] + redBuf[1][tid]
                          + redBuf[2][tid] + redBuf[3][tid];
}

extern "C" void kernel_launch(void* const* d_in, const int* in_sizes, int n_in,
                              void* d_out, int out_size, void* d_ws, size_t ws_size,
                              hipStream_t stream) {
    const float* inputs = (const float*)d_in[0];   // [1024,12] f32
    const float* thetas = (const float*)d_in[1];   // [72] f32
    float* out = (float*)d_out;                    // [1024,12] f32
    vqc_kernel<<<dim3(1024), dim3(256), 0, stream>>>(inputs, thetas, out);
}

// Round 7
// 78.034 us; speedup vs baseline: 1.3039x; 1.0045x over previous
//
#include <hip/hip_runtime.h>

// VQC 12-qubit statevector, batch=1024. One block = 256 thr = 4 waves = ONE
// batch element; each wave holds 16 float2 amps. Grid 1024 -> 4 blocks/CU.
// Flat index i (12 bits), qubit q <-> bit (11-q).
// Layout A: b11b10 = w (q0,q1); b9..b6 = reg (q2..q5); b5..b0 = lane (q6..q11)
// Layout B: b11b10 = w (q0,q1); b9..b4 = lane (q2..q7); b3..b0 = reg (q8..q11)
// Layer 0 folds into the closed-form product-state init. Per remaining layer:
// BA exchange fuses CNOT Gray perm (new[y]=old[y^(y>>1)]) + that layer's
// Y_q0,Y_q1; Y q2..q5 in-reg [A]; AB exchange fuses Y_q6,Y_q7 (wave-local,
// ZERO barriers); Y q8..q11 in-reg [B]; fused Z. Last layer's Zs dropped.
// R7 vs R6 (DS-pipe is the bottleneck - R3==R6 time showed occupancy can't
// help while per-CU DS work is constant):
//  - amps staged in LDS as packed f16x2 (RN): 4 taps of each output amp are
//    16B contiguous -> ONE ds_read_b128 per amp; writes b32. DS insts ~-40%,
//    LDS bytes -50%. Error budget: 4 roundtrips ~2e-3 rel -> OK vs 1.7e-2.
//  - XOR bank swizzle on group index (reads spread 8/quad = floor; BA writes
//    8-way accepted, AB writes 2-way free).
//  - separate BA (16KB) / AB (16KB) buffers: AB needs no barriers at all;
//    block barriers 6 -> 4.
//  - fork-trick readout: 45 shuffles for all 12 reductions (was 72).

#define PI_F 3.14159265358979323846f
#define NR 16

typedef _Float16 half2v __attribute__((ext_vector_type(2)));

__device__ __forceinline__ unsigned packh(float2 a) {
    half2v h; h.x = (_Float16)a.x; h.y = (_Float16)a.y;   // RN converts
    return __builtin_bit_cast(unsigned, h);
}
__device__ __forceinline__ float lo16(unsigned u) {
    return (float)__builtin_bit_cast(half2v, u).x;
}
__device__ __forceinline__ float hi16(unsigned u) {
    return (float)__builtin_bit_cast(half2v, u).y;
}
__device__ __forceinline__ float2 cmul(float2 a, float2 b) {
    return make_float2(a.x*b.x - a.y*b.y, a.x*b.y + a.y*b.x);
}

template<int RB>
__device__ __forceinline__ void ypow_reg(float2 (&a)[NR], float c, float s) {
    #pragma unroll
    for (int r0 = 0; r0 < NR; ++r0) {
        if ((r0 >> RB) & 1) continue;
        const int r1 = r0 | (1 << RB);
        float2 a0 = a[r0], a1 = a[r1];
        a[r0] = make_float2(c*a0.x - s*a1.x, c*a0.y - s*a1.y);
        a[r1] = make_float2(s*a0.x + c*a1.x, s*a0.y + c*a1.y);
    }
}

// Layout B -> A. Fuses CNOT chain + next-applied Y_q0,Y_q1.
// All 4 taps of an output amp share (u = x9^v1 = y9, t = x8..x0) -> colocated
// 16B group at dword addr 4*(g ^ (t>>4)) + tap, tap = (v1<<1)|v0, g = u<<9|t.
__device__ __forceinline__ void exchange_BA(float2 (&a)[NR], unsigned* buf,
                                            int w, int lane,
                                            float c0, float s0, float c1, float s1,
                                            bool first) {
    if (!first) __syncthreads();           // prior block-wide BA reads done
    {
        const int v0 = (w >> 1) & 1;       // x11
        const int v1 = v0 ^ (w & 1);       // x10^x11
        const int u  = (lane >> 5) ^ v1;   // y9
        const int tap = (v1 << 1) | v0;
        // g = (u<<9)|t, t = ((lane&31)<<4)|r ; swizzled g' = g ^ (t>>4) = g^(lane&31)
        const int gx = ((u << 9) | ((lane & 31) << 4)) ^ (lane & 31);
        #pragma unroll
        for (int r = 0; r < NR; ++r)
            buf[((gx ^ r) << 2) | tap] = packh(a[r]);
    }
    __syncthreads();
    // K[(y11,y10)][(v0,v1)] = Y0[y11,v0] * Y1[y10,v1], Y = [[c,-s],[s,c]]
    const float y0a = (w & 2) ? s0 : c0;
    const float y0b = (w & 2) ? c0 : -s0;
    const float y1a = (w & 1) ? s1 : c1;
    const float y1b = (w & 1) ? c1 : -s1;
    const float K00 = y0a*y1a, K01 = y0a*y1b, K10 = y0b*y1a, K11 = y0b*y1b;
    #pragma unroll
    for (int rp = 0; rp < NR; ++rp) {
        const int ylow = (rp << 6) | lane;         // y9..y0
        const int t = (ylow ^ (ylow >> 1)) & 511;  // x8..x0
        const int g = ((rp >> 3) << 9) | t;        // u = y9
        const int gp = g ^ (t >> 4);
        const uint4 d = *(const uint4*)(buf + (gp << 2));
        // d.x=(v0=0,v1=0)=i00  d.y=(1,0)=i10  d.z=(0,1)=i01  d.w=(1,1)=i11
        a[rp].x = K00*lo16(d.x) + K01*lo16(d.z) + K10*lo16(d.y) + K11*lo16(d.w);
        a[rp].y = K00*hi16(d.x) + K01*hi16(d.z) + K10*hi16(d.y) + K11*hi16(d.w);
    }
}

// Layout A -> B, fusing Y_q6,Y_q7. Wave-local region, same-wave LDS ops are
// in-order -> NO barriers. Group (q2..q5, q8..q11), tap = (q6<<1)|q7.
__device__ __forceinline__ void exchange_AB(float2 (&a)[NR], unsigned* wbuf,
                                            int lane,
                                            float c6, float s6, float c7, float s7) {
    {
        const int tap = lane >> 4;             // old (q6,q7)
        const int m = lane & 15;               // q8..q11
        #pragma unroll
        for (int r = 0; r < NR; ++r)           // g = (r<<4)|m, swizzled: low4 ^= r
            wbuf[(((r << 4) | (m ^ r)) << 2) | tap] = packh(a[r]);
    }
    const int j = lane & 3;                    // new (q6,q7)
    const float e0 = (j & 2) ? s6 : c6;
    const float e1 = (j & 2) ? c6 : -s6;
    const float f0 = (j & 1) ? s7 : c7;
    const float f1 = (j & 1) ? c7 : -s7;
    const float C0 = e0*f0, C1 = e0*f1, C2 = e1*f0, C3 = e1*f1;
    const int row = lane >> 2;                 // q2..q5
    #pragma unroll
    for (int rp = 0; rp < NR; ++rp) {
        const int gp = (row << 4) | (rp ^ row);
        const uint4 d = *(const uint4*)(wbuf + (gp << 2));
        a[rp].x = C0*lo16(d.x) + C1*lo16(d.y) + C2*lo16(d.z) + C3*lo16(d.w);
        a[rp].y = C0*hi16(d.x) + C1*hi16(d.y) + C2*hi16(d.z) + C3*hi16(d.w);
    }
}

// Fused Z, all 12 qubits, layout B.
__device__ __forceinline__ void fused_z_B(float2 (&a)[NR], int w, int lane,
                                          const float* __restrict__ th) {
    float alpha = 0.0f;
    if (w & 2) alpha += th[1];                  // q0
    if (w & 1) alpha += th[3];                  // q1
    #pragma unroll
    for (int k = 0; k < 6; ++k)                 // lane bit k <-> q(7-k)
        alpha += ((lane >> k) & 1) ? th[2*(7-k)+1] : 0.0f;
    float2 cA; __sincosf(PI_F * alpha, &cA.y, &cA.x);
    float2 z8, z9, z10, z11;
    __sincosf(PI_F * th[17], &z8.y,  &z8.x);
    __sincosf(PI_F * th[19], &z9.y,  &z9.x);
    __sincosf(PI_F * th[21], &z10.y, &z10.x);
    __sincosf(PI_F * th[23], &z11.y, &z11.x);
    float2 hi[4], lo[4];
    hi[0] = cA;                    hi[1] = cmul(cA, z9);
    hi[2] = cmul(cA, z8);          hi[3] = cmul(hi[2], z9);
    lo[0] = make_float2(1.f, 0.f); lo[1] = z11;
    lo[2] = z10;                   lo[3] = cmul(z10, z11);
    #pragma unroll
    for (int r = 0; r < NR; ++r)
        a[r] = cmul(cmul(a[r], hi[r >> 2]), lo[r & 3]);
}

// Product-state init in layout B; all of layer 0's single-qubit gates folded.
__device__ __forceinline__ void encode_init(float2 (&a)[NR], int w, int lane,
                                            const float* __restrict__ x,
                                            const float* __restrict__ th0) {
    float2 F = make_float2(0.015625f, 0.0f);
    #pragma unroll
    for (int q = 0; q < 8; ++q) {
        float2 ex; __sincosf(PI_F * x[q], &ex.y, &ex.x);
        float sy, cy; __sincosf(0.5f * PI_F * th0[2*q], &sy, &cy);
        float2 cz; __sincosf(PI_F * th0[2*q+1], &cz.y, &cz.x);
        float2 u0 = make_float2(cy - sy*ex.x, -sy*ex.y);
        float2 u1 = cmul(cz, make_float2(sy + cy*ex.x, cy*ex.y));
        int bit;
        if (q == 0)      bit = (w >> 1) & 1;
        else if (q == 1) bit = w & 1;
        else             bit = (lane >> (7 - q)) & 1;
        F = cmul(F, bit ? u1 : u0);
    }
    float2 v0[4], v1[4];                        // q8..q11
    #pragma unroll
    for (int q = 8; q < 12; ++q) {
        float2 ex; __sincosf(PI_F * x[q], &ex.y, &ex.x);
        float sy, cy; __sincosf(0.5f * PI_F * th0[2*q], &sy, &cy);
        float2 cz; __sincosf(PI_F * th0[2*q+1], &cz.y, &cz.x);
        v0[q-8] = make_float2(cy - sy*ex.x, -sy*ex.y);
        v1[q-8] = cmul(cz, make_float2(sy + cy*ex.x, cy*ex.y));
    }
    float2 hi[4], lo[4];
    hi[0] = cmul(v0[0], v0[1]); hi[1] = cmul(v0[0], v1[1]);
    hi[2] = cmul(v1[0], v0[1]); hi[3] = cmul(v1[0], v1[1]);
    lo[0] = cmul(v0[2], v0[3]); lo[1] = cmul(v0[2], v1[3]);
    lo[2] = cmul(v1[2], v0[3]); lo[3] = cmul(v1[2], v1[3]);
    #pragma unroll
    for (int t = 0; t < 4; ++t) hi[t] = cmul(F, hi[t]);
    #pragma unroll
    for (int r = 0; r < NR; ++r)
        a[r] = cmul(hi[r >> 2], lo[r & 3]);
}

__global__ __launch_bounds__(256) void vqc_kernel(
    const float* __restrict__ inputs,   // [1024,12]
    const float* __restrict__ thetas,   // [72] = [3][12][2]
    float* __restrict__ out)            // [1024,12]
{
    __shared__ __align__(16) unsigned bufBA[4096];   // 1024 groups x 16B
    __shared__ __align__(16) unsigned bufAB[4096];   // 4 waves x 256 groups x 16B
    __shared__ float redBuf[4][12];

    const int b = blockIdx.x;
    const int tid = threadIdx.x;
    const int w = tid >> 6;
    const int lane = tid & 63;
    const float* x = inputs + b * 12;
    const float* th1 = thetas + 24;
    const float* th2 = thetas + 48;

    float2 a[NR];
    encode_init(a, w, lane, x, thetas);     // all of layer 0's 1q gates

    // Layer-0 CNOT chain, fused with layer-1 Y_q0, Y_q1
    { float s0,c0,s1,c1;
      __sincosf(0.5f*PI_F*th1[0], &s0, &c0);
      __sincosf(0.5f*PI_F*th1[2], &s1, &c1);
      exchange_BA(a, bufBA, w, lane, c0, s0, c1, s1, true); }

    // ---- Layer 1 ----
    { float s,c; __sincosf(0.5f*PI_F*th1[4],  &s,&c); ypow_reg<3>(a,c,s); }  // q2
    { float s,c; __sincosf(0.5f*PI_F*th1[6],  &s,&c); ypow_reg<2>(a,c,s); }  // q3
    { float s,c; __sincosf(0.5f*PI_F*th1[8],  &s,&c); ypow_reg<1>(a,c,s); }  // q4
    { float s,c; __sincosf(0.5f*PI_F*th1[10], &s,&c); ypow_reg<0>(a,c,s); }  // q5
    { float s6,c6,s7,c7;
      __sincosf(0.5f*PI_F*th1[12], &s6,&c6);
      __sincosf(0.5f*PI_F*th1[14], &s7,&c7);
      exchange_AB(a, bufAB + w * 1024, lane, c6, s6, c7, s7); }
    { float s,c; __sincosf(0.5f*PI_F*th1[16], &s,&c); ypow_reg<3>(a,c,s); }  // q8
    { float s,c; __sincosf(0.5f*PI_F*th1[18], &s,&c); ypow_reg<2>(a,c,s); }  // q9
    { float s,c; __sincosf(0.5f*PI_F*th1[20], &s,&c); ypow_reg<1>(a,c,s); }  // q10
    { float s,c; __sincosf(0.5f*PI_F*th1[22], &s,&c); ypow_reg<0>(a,c,s); }  // q11
    fused_z_B(a, w, lane, th1);

    // Layer-1 CNOT chain, fused with layer-2 Y_q0, Y_q1
    { float s0,c0,s1,c1;
      __sincosf(0.5f*PI_F*th2[0], &s0, &c0);
      __sincosf(0.5f*PI_F*th2[2], &s1, &c1);
      exchange_BA(a, bufBA, w, lane, c0, s0, c1, s1, false); }

    // ---- Layer 2 (no CNOT; Zs dropped — diagonal before |amp|^2) ----
    { float s,c; __sincosf(0.5f*PI_F*th2[4],  &s,&c); ypow_reg<3>(a,c,s); }
    { float s,c; __sincosf(0.5f*PI_F*th2[6],  &s,&c); ypow_reg<2>(a,c,s); }
    { float s,c; __sincosf(0.5f*PI_F*th2[8],  &s,&c); ypow_reg<1>(a,c,s); }
    { float s,c; __sincosf(0.5f*PI_F*th2[10], &s,&c); ypow_reg<0>(a,c,s); }
    { float s6,c6,s7,c7;
      __sincosf(0.5f*PI_F*th2[12], &s6,&c6);
      __sincosf(0.5f*PI_F*th2[14], &s7,&c7);
      exchange_AB(a, bufAB + w * 1024, lane, c6, s6, c7, s7); }
    { float s,c; __sincosf(0.5f*PI_F*th2[16], &s,&c); ypow_reg<3>(a,c,s); }
    { float s,c; __sincosf(0.5f*PI_F*th2[18], &s,&c); ypow_reg<2>(a,c,s); }
    { float s,c; __sincosf(0.5f*PI_F*th2[20], &s,&c); ypow_reg<1>(a,c,s); }
    { float s,c; __sincosf(0.5f*PI_F*th2[22], &s,&c); ypow_reg<0>(a,c,s); }

    // ---- Readout (layout B). Fork-trick: one butterfly of sums, forking the
    // difference at each stage; fork at stage k then reduced over the rest.
    float P = 0.0f, D0 = 0, D1 = 0, D2 = 0, D3 = 0;
    #pragma unroll
    for (int r = 0; r < NR; ++r) {
        const float p = a[r].x * a[r].x + a[r].y * a[r].y;
        P += p;
        D0 += (r & 1) ? -p : p;
        D1 += (r & 2) ? -p : p;
        D2 += (r & 4) ? -p : p;
        D3 += (r & 8) ? -p : p;
    }
    float f[6];                      // f[k] <-> lane bit (5-k) <-> qubit q(2+k)
    float m = P;
    #pragma unroll
    for (int k = 0; k < 6; ++k) {
        float p = __shfl_xor(m, 32 >> k, 64);
        f[k] = m - p;
        m = m + p;
    }
    #pragma unroll
    for (int k = 0; k < 6; ++k) {
        #pragma unroll
        for (int s = 16 >> k; s >= 1; s >>= 1)
            f[k] += __shfl_xor(f[k], s, 64);
    }
    #pragma unroll
    for (int s = 32; s >= 1; s >>= 1) {
        D0 += __shfl_xor(D0, s, 64);
        D1 += __shfl_xor(D1, s, 64);
        D2 += __shfl_xor(D2, s, 64);
        D3 += __shfl_xor(D3, s, 64);
    }
    if (lane == 0) {
        float* rb = redBuf[w];
        rb[0] = (w & 2) ? -m : m;    // q0 = wave bit 1
        rb[1] = (w & 1) ? -m : m;    // q1 = wave bit 0
        rb[2] = f[0]; rb[3] = f[1]; rb[4] = f[2];
        rb[5] = f[3]; rb[6] = f[4]; rb[7] = f[5];
        rb[8] = D3; rb[9] = D2; rb[10] = D1; rb[11] = D0;   // q8..q11
    }
    __syncthreads();
    if (tid < 12)
        out[b * 12 + tid] = redBuf[0][tid] + redBuf[1][tid]
                          + redBuf[2][tid] + redBuf[3][tid];
}

extern "C" void kernel_launch(void* const* d_in, const int* in_sizes, int n_in,
                              void* d_out, int out_size, void* d_ws, size_t ws_size,
                              hipStream_t stream) {
    const float* inputs = (const float*)d_in[0];   // [1024,12] f32
    const float* thetas = (const float*)d_in[1];   // [72] f32
    float* out = (float*)d_out;                    // [1024,12] f32
    vqc_kernel<<<dim3(1024), dim3(256), 0, stream>>>(inputs, thetas, out);
}

// Round 8
// 77.457 us; speedup vs baseline: 1.3136x; 1.0075x over previous
//
#include <hip/hip_runtime.h>

// VQC 12-qubit statevector, batch=1024. Two kernels:
//  setup_kernel: precomputes ALL trig into a d_ws table (theta-derived trig is
//    identical across every thread of the main kernel - ~68 redundant sincos
//    per thread removed; x-trig identical across each block's 256 threads -
//    ~36 more). ~12.3K sincos total vs 21M before.
//  vqc_kernel: R7 structure (1 elem/block, 4 waves, f16 LDS staging, fused
//    exchanges) with coefficients from the table via wave-uniform loads
//    (s_load -> SGPR broadcast). Only 2 per-thread sincos remain (fused-Z
//    alpha, lane-dependent).
// Table layout (floats): [0..143] (l,q): {yc,ys,zc,zs} = cos/sin(pi/2*thY),
//   cos/sin(pi*thZ); [144..144+24576) elem b, qubit q: {cos(pi x), sin(pi x)}.
// Layouts/fusions as R7:
//  A: b11b10=w(q0,q1); b9..b6=reg(q2..q5); b5..b0=lane(q6..q11)
//  B: b11b10=w(q0,q1); b9..b4=lane(q2..q7); b3..b0=reg(q8..q11)
// Layer 0 folds into closed-form product init; BA exchange fuses CNOT Gray
// perm + next Y_q0,Y_q1; AB fuses Y_q6,Y_q7 (wave-local, no barriers); last
// layer's Zs dropped (diagonal before |amp|^2 readout).

#define PI_F 3.14159265358979323846f
#define NR 16

typedef _Float16 half2v __attribute__((ext_vector_type(2)));

__device__ __forceinline__ unsigned packh(float2 a) {
    half2v h; h.x = (_Float16)a.x; h.y = (_Float16)a.y;
    return __builtin_bit_cast(unsigned, h);
}
__device__ __forceinline__ float lo16(unsigned u) {
    return (float)__builtin_bit_cast(half2v, u).x;
}
__device__ __forceinline__ float hi16(unsigned u) {
    return (float)__builtin_bit_cast(half2v, u).y;
}
__device__ __forceinline__ float2 cmul(float2 a, float2 b) {
    return make_float2(a.x*b.x - a.y*b.y, a.x*b.y + a.y*b.x);
}

__global__ __launch_bounds__(256) void setup_kernel(
    const float* __restrict__ inputs,   // [1024,12]
    const float* __restrict__ thetas,   // [72]
    float* __restrict__ tbl)
{
    const int t = blockIdx.x * 256 + threadIdx.x;
    if (t < 36) {                       // (l,q) theta trig
        const int l = t / 12, q = t - l * 12;
        float ys, yc, zs, zc;
        __sincosf(0.5f * PI_F * thetas[l * 24 + 2 * q], &ys, &yc);
        __sincosf(PI_F * thetas[l * 24 + 2 * q + 1], &zs, &zc);
        float* o = tbl + t * 4;
        o[0] = yc; o[1] = ys; o[2] = zc; o[3] = zs;
    }
    if (t < 12288) {                    // x trig (1024*12)
        float s, c; __sincosf(PI_F * inputs[t], &s, &c);
        tbl[144 + 2 * t] = c; tbl[144 + 2 * t + 1] = s;
    }
}

template<int RB>
__device__ __forceinline__ void ypow_reg(float2 (&a)[NR], float c, float s) {
    #pragma unroll
    for (int r0 = 0; r0 < NR; ++r0) {
        if ((r0 >> RB) & 1) continue;
        const int r1 = r0 | (1 << RB);
        float2 a0 = a[r0], a1 = a[r1];
        a[r0] = make_float2(c*a0.x - s*a1.x, c*a0.y - s*a1.y);
        a[r1] = make_float2(s*a0.x + c*a1.x, s*a0.y + c*a1.y);
    }
}

// Layout B -> A. Fuses CNOT chain + next-applied Y_q0,Y_q1. (R7-verified.)
__device__ __forceinline__ void exchange_BA(float2 (&a)[NR], unsigned* buf,
                                            int w, int lane,
                                            float c0, float s0, float c1, float s1,
                                            bool first) {
    if (!first) __syncthreads();
    {
        const int v0 = (w >> 1) & 1;       // x11
        const int v1 = v0 ^ (w & 1);       // x10^x11
        const int u  = (lane >> 5) ^ v1;   // y9
        const int tap = (v1 << 1) | v0;
        const int gx = ((u << 9) | ((lane & 31) << 4)) ^ (lane & 31);
        #pragma unroll
        for (int r = 0; r < NR; ++r)
            buf[((gx ^ r) << 2) | tap] = packh(a[r]);
    }
    __syncthreads();
    const float y0a = (w & 2) ? s0 : c0;
    const float y0b = (w & 2) ? c0 : -s0;
    const float y1a = (w & 1) ? s1 : c1;
    const float y1b = (w & 1) ? c1 : -s1;
    const float K00 = y0a*y1a, K01 = y0a*y1b, K10 = y0b*y1a, K11 = y0b*y1b;
    #pragma unroll
    for (int rp = 0; rp < NR; ++rp) {
        const int ylow = (rp << 6) | lane;
        const int t = (ylow ^ (ylow >> 1)) & 511;
        const int g = ((rp >> 3) << 9) | t;
        const int gp = g ^ (t >> 4);
        const uint4 d = *(const uint4*)(buf + (gp << 2));
        a[rp].x = K00*lo16(d.x) + K01*lo16(d.z) + K10*lo16(d.y) + K11*lo16(d.w);
        a[rp].y = K00*hi16(d.x) + K01*hi16(d.z) + K10*hi16(d.y) + K11*hi16(d.w);
    }
}

// Layout A -> B, fusing Y_q6,Y_q7. Wave-local; no barriers. (R7-verified.)
__device__ __forceinline__ void exchange_AB(float2 (&a)[NR], unsigned* wbuf,
                                            int lane,
                                            float c6, float s6, float c7, float s7) {
    {
        const int tap = lane >> 4;
        const int m = lane & 15;
        #pragma unroll
        for (int r = 0; r < NR; ++r)
            wbuf[(((r << 4) | (m ^ r)) << 2) | tap] = packh(a[r]);
    }
    const int j = lane & 3;
    const float e0 = (j & 2) ? s6 : c6;
    const float e1 = (j & 2) ? c6 : -s6;
    const float f0 = (j & 1) ? s7 : c7;
    const float f1 = (j & 1) ? c7 : -s7;
    const float C0 = e0*f0, C1 = e0*f1, C2 = e1*f0, C3 = e1*f1;
    const int row = lane >> 2;
    #pragma unroll
    for (int rp = 0; rp < NR; ++rp) {
        const int gp = (row << 4) | (rp ^ row);
        const uint4 d = *(const uint4*)(wbuf + (gp << 2));
        a[rp].x = C0*lo16(d.x) + C1*lo16(d.y) + C2*lo16(d.z) + C3*lo16(d.w);
        a[rp].y = C0*hi16(d.x) + C1*hi16(d.y) + C2*hi16(d.z) + C3*hi16(d.w);
    }
}

// Fused Z, all 12 qubits, layout B. alpha needs a per-lane angle sum -> one
// sincos; q8..q11 factors come from the table.
__device__ __forceinline__ void fused_z_B(float2 (&a)[NR], int w, int lane,
                                          const float* __restrict__ th,
                                          const float4* __restrict__ TQ) {
    float alpha = 0.0f;
    if (w & 2) alpha += th[1];                  // q0
    if (w & 1) alpha += th[3];                  // q1
    #pragma unroll
    for (int k = 0; k < 6; ++k)                 // lane bit k <-> q(7-k)
        alpha += ((lane >> k) & 1) ? th[2*(7-k)+1] : 0.0f;
    float2 cA; __sincosf(PI_F * alpha, &cA.y, &cA.x);
    const float4 t8 = TQ[8], t9 = TQ[9], t10 = TQ[10], t11 = TQ[11];
    const float2 z8  = make_float2(t8.z,  t8.w);
    const float2 z9  = make_float2(t9.z,  t9.w);
    const float2 z10 = make_float2(t10.z, t10.w);
    const float2 z11 = make_float2(t11.z, t11.w);
    float2 hi[4], lo[4];
    hi[0] = cA;                    hi[1] = cmul(cA, z9);
    hi[2] = cmul(cA, z8);          hi[3] = cmul(hi[2], z9);
    lo[0] = make_float2(1.f, 0.f); lo[1] = z11;
    lo[2] = z10;                   lo[3] = cmul(z10, z11);
    #pragma unroll
    for (int r = 0; r < NR; ++r)
        a[r] = cmul(cmul(a[r], hi[r >> 2]), lo[r & 3]);
}

// Product-state init in layout B from tables; all of layer 0's 1q gates.
__device__ __forceinline__ void encode_init(float2 (&a)[NR], int w, int lane,
                                            const float2* __restrict__ XT,
                                            const float4* __restrict__ TQ0) {
    float2 F = make_float2(0.015625f, 0.0f);
    #pragma unroll
    for (int q = 0; q < 8; ++q) {
        const float2 ex = XT[q];
        const float4 t = TQ0[q];                // {yc,ys,zc,zs}
        float2 u0 = make_float2(t.x - t.y*ex.x, -t.y*ex.y);
        float2 u1 = cmul(make_float2(t.z, t.w),
                         make_float2(t.y + t.x*ex.x, t.x*ex.y));
        int bit;
        if (q == 0)      bit = (w >> 1) & 1;
        else if (q == 1) bit = w & 1;
        else             bit = (lane >> (7 - q)) & 1;
        F = cmul(F, bit ? u1 : u0);
    }
    float2 v0[4], v1[4];                        // q8..q11
    #pragma unroll
    for (int q = 8; q < 12; ++q) {
        const float2 ex = XT[q];
        const float4 t = TQ0[q];
        v0[q-8] = make_float2(t.x - t.y*ex.x, -t.y*ex.y);
        v1[q-8] = cmul(make_float2(t.z, t.w),
                       make_float2(t.y + t.x*ex.x, t.x*ex.y));
    }
    float2 hi[4], lo[4];
    hi[0] = cmul(v0[0], v0[1]); hi[1] = cmul(v0[0], v1[1]);
    hi[2] = cmul(v1[0], v0[1]); hi[3] = cmul(v1[0], v1[1]);
    lo[0] = cmul(v0[2], v0[3]); lo[1] = cmul(v0[2], v1[3]);
    lo[2] = cmul(v1[2], v0[3]); lo[3] = cmul(v1[2], v1[3]);
    #pragma unroll
    for (int t = 0; t < 4; ++t) hi[t] = cmul(F, hi[t]);
    #pragma unroll
    for (int r = 0; r < NR; ++r)
        a[r] = cmul(hi[r >> 2], lo[r & 3]);
}

__global__ __launch_bounds__(256) void vqc_kernel(
    const float* __restrict__ tbl,      // trig table (d_ws)
    const float* __restrict__ thetas,   // [72] raw (for alpha sums)
    float* __restrict__ out)            // [1024,12]
{
    __shared__ __align__(16) unsigned bufBA[4096];   // 16 KB
    __shared__ __align__(16) unsigned bufAB[4096];   // 16 KB (4 wave regions)
    __shared__ float redBuf[4][12];

    const int b = blockIdx.x;
    const int tid = threadIdx.x;
    const int w = tid >> 6;
    const int lane = tid & 63;

    const float4* TQ = (const float4*)tbl;               // [(l*12+q)]
    const float2* XT = (const float2*)(tbl + 144) + b * 12;
    const float* th1 = thetas + 24;
    const float* th2 = thetas + 48;

    float2 a[NR];
    encode_init(a, w, lane, XT, TQ);        // all of layer 0's 1q gates

    // Layer-0 CNOT chain, fused with layer-1 Y_q0, Y_q1
    { const float4 t0 = TQ[12], t1 = TQ[13];
      exchange_BA(a, bufBA, w, lane, t0.x, t0.y, t1.x, t1.y, true); }

    // ---- Layer 1 ----
    { const float4 t = TQ[14]; ypow_reg<3>(a, t.x, t.y); }   // q2
    { const float4 t = TQ[15]; ypow_reg<2>(a, t.x, t.y); }   // q3
    { const float4 t = TQ[16]; ypow_reg<1>(a, t.x, t.y); }   // q4
    { const float4 t = TQ[17]; ypow_reg<0>(a, t.x, t.y); }   // q5
    { const float4 t6 = TQ[18], t7 = TQ[19];
      exchange_AB(a, bufAB + w * 1024, lane, t6.x, t6.y, t7.x, t7.y); }
    { const float4 t = TQ[20]; ypow_reg<3>(a, t.x, t.y); }   // q8
    { const float4 t = TQ[21]; ypow_reg<2>(a, t.x, t.y); }   // q9
    { const float4 t = TQ[22]; ypow_reg<1>(a, t.x, t.y); }   // q10
    { const float4 t = TQ[23]; ypow_reg<0>(a, t.x, t.y); }   // q11
    fused_z_B(a, w, lane, th1, TQ + 12);

    // Layer-1 CNOT chain, fused with layer-2 Y_q0, Y_q1
    { const float4 t0 = TQ[24], t1 = TQ[25];
      exchange_BA(a, bufBA, w, lane, t0.x, t0.y, t1.x, t1.y, false); }

    // ---- Layer 2 (no CNOT; Zs dropped — diagonal before |amp|^2) ----
    { const float4 t = TQ[26]; ypow_reg<3>(a, t.x, t.y); }
    { const float4 t = TQ[27]; ypow_reg<2>(a, t.x, t.y); }
    { const float4 t = TQ[28]; ypow_reg<1>(a, t.x, t.y); }
    { const float4 t = TQ[29]; ypow_reg<0>(a, t.x, t.y); }
    { const float4 t6 = TQ[30], t7 = TQ[31];
      exchange_AB(a, bufAB + w * 1024, lane, t6.x, t6.y, t7.x, t7.y); }
    { const float4 t = TQ[32]; ypow_reg<3>(a, t.x, t.y); }
    { const float4 t = TQ[33]; ypow_reg<2>(a, t.x, t.y); }
    { const float4 t = TQ[34]; ypow_reg<1>(a, t.x, t.y); }
    { const float4 t = TQ[35]; ypow_reg<0>(a, t.x, t.y); }

    // ---- Readout (layout B), fork-trick reduction ----
    float P = 0.0f, D0 = 0, D1 = 0, D2 = 0, D3 = 0;
    #pragma unroll
    for (int r = 0; r < NR; ++r) {
        const float p = a[r].x * a[r].x + a[r].y * a[r].y;
        P += p;
        D0 += (r & 1) ? -p : p;
        D1 += (r & 2) ? -p : p;
        D2 += (r & 4) ? -p : p;
        D3 += (r & 8) ? -p : p;
    }
    float f[6];
    float m = P;
    #pragma unroll
    for (int k = 0; k < 6; ++k) {
        float p = __shfl_xor(m, 32 >> k, 64);
        f[k] = m - p;
        m = m + p;
    }
    #pragma unroll
    for (int k = 0; k < 6; ++k) {
        #pragma unroll
        for (int s = 16 >> k; s >= 1; s >>= 1)
            f[k] += __shfl_xor(f[k], s, 64);
    }
    #pragma unroll
    for (int s = 32; s >= 1; s >>= 1) {
        D0 += __shfl_xor(D0, s, 64);
        D1 += __shfl_xor(D1, s, 64);
        D2 += __shfl_xor(D2, s, 64);
        D3 += __shfl_xor(D3, s, 64);
    }
    if (lane == 0) {
        float* rb = redBuf[w];
        rb[0] = (w & 2) ? -m : m;
        rb[1] = (w & 1) ? -m : m;
        rb[2] = f[0]; rb[3] = f[1]; rb[4] = f[2];
        rb[5] = f[3]; rb[6] = f[4]; rb[7] = f[5];
        rb[8] = D3; rb[9] = D2; rb[10] = D1; rb[11] = D0;
    }
    __syncthreads();
    if (tid < 12)
        out[b * 12 + tid] = redBuf[0][tid] + redBuf[1][tid]
                          + redBuf[2][tid] + redBuf[3][tid];
}

extern "C" void kernel_launch(void* const* d_in, const int* in_sizes, int n_in,
                              void* d_out, int out_size, void* d_ws, size_t ws_size,
                              hipStream_t stream) {
    const float* inputs = (const float*)d_in[0];   // [1024,12] f32
    const float* thetas = (const float*)d_in[1];   // [72] f32
    float* out = (float*)d_out;                    // [1024,12] f32
    float* tbl = (float*)d_ws;                     // 144 + 24576 floats
    setup_kernel<<<dim3(48), dim3(256), 0, stream>>>(inputs, thetas, tbl);
    vqc_kernel<<<dim3(1024), dim3(256), 0, stream>>>(tbl, thetas, out);
}